// Round 3
// baseline (523.137 us; speedup 1.0000x reference)
//
#include <hip/hip_runtime.h>
#include <hip/hip_bf16.h>
#include <hip/hip_fp16.h>

#define N_NODES 50000
#define N_EDGES 1600000
#define HEADS 8
#define HD 32
#define FIN 256
#define HID 256

typedef unsigned short u16;
typedef unsigned int u32;

typedef short s8v __attribute__((ext_vector_type(8)));   // 8 bf16 (4 VGPRs)
typedef float f4v __attribute__((ext_vector_type(4)));   // 4 fp32 acc

// pack 2 fp32 -> 2 bf16 (RNE) in one u32; lowers to v_cvt_pk_bf16_f32 on gfx950
__device__ __forceinline__ u32 pk2(float lo, float hi) {
  __hip_bfloat162 b = __float22bfloat162_rn(make_float2(lo, hi));
  union { __hip_bfloat162 b2; u32 u; } c;
  c.b2 = b;
  return c.u;
}

// ---------------- MFMA GEMM + fused attn projections ------------------------
// H[n][h*32+d] = X[n,:] @ W[h,:,d] + bw[h,d], stored **f16** (better precision
// than bf16 AND enables v_fma_mix_f32 in the gather kernel).
__global__ __launch_bounds__(256) void k_gemm(
    const float* __restrict__ X, const float* __restrict__ W,
    const float* __restrict__ bw, const float* __restrict__ A,
    __half* __restrict__ Hb, float* __restrict__ si, float* __restrict__ sj) {
  __shared__ __align__(16) u16 Xs[128 * 40];  // [row][k] stride 40 (2-way max)
  __shared__ __align__(16) u16 Wt[128 * 40];  // [col][k] stride 40

  const int t = threadIdx.x;
  const int m0 = (blockIdx.x >> 1) * 128;
  const int n0 = (blockIdx.x & 1) * 128;
  const int w = t >> 6;
  const int lane = t & 63;
  const int l15 = lane & 15;
  const int quad = lane >> 4;
  const int wm = (w >> 1) * 64;   // wave row offset in block tile
  const int wn = (w & 1) * 64;    // wave col offset in block tile

  f4v acc[4][4];
#pragma unroll
  for (int i = 0; i < 4; i++)
#pragma unroll
    for (int j = 0; j < 4; j++) acc[i][j] = (f4v){0.f, 0.f, 0.f, 0.f};

  // W staging assignment (constant over k-loop)
  const int nl = t & 127;          // local col
  const int half = t >> 7;         // k half (0/1): kk = half*16 + i
  const int gn = n0 + nl;
  const int gh = gn >> 5, gd = gn & 31;

  for (int k0 = 0; k0 < FIN; k0 += 32) {
    // stage X tile: 128 rows x 32 k (fp32 -> bf16)
#pragma unroll
    for (int p = 0; p < 4; p++) {
      int row = p * 32 + (t >> 3);
      int f4 = t & 7;
      int node = m0 + row;
      float4 xv = make_float4(0.f, 0.f, 0.f, 0.f);
      if (node < N_NODES) xv = *(const float4*)&X[node * FIN + k0 + f4 * 4];
      u32* dst = (u32*)&Xs[row * 40 + f4 * 4];
      dst[0] = pk2(xv.x, xv.y);
      dst[1] = pk2(xv.z, xv.w);
    }
    // stage W tile transposed: Wt[col][kk] = W[h][k0+kk][d]
    {
      const float* wp = W + gh * (FIN * HD) + (k0 + half * 16) * HD + gd;
#pragma unroll
      for (int j = 0; j < 8; j++) {
        float lo = wp[(2 * j) * HD];
        float hi = wp[(2 * j + 1) * HD];
        *(u32*)&Wt[nl * 40 + half * 16 + 2 * j] = pk2(lo, hi);
      }
    }
    __syncthreads();
    s8v af[4], bf[4];
#pragma unroll
    for (int mi = 0; mi < 4; mi++)
      af[mi] = *(const s8v*)&Xs[(wm + mi * 16 + l15) * 40 + quad * 8];
#pragma unroll
    for (int ni = 0; ni < 4; ni++)
      bf[ni] = *(const s8v*)&Wt[(wn + ni * 16 + l15) * 40 + quad * 8];
#pragma unroll
    for (int mi = 0; mi < 4; mi++)
#pragma unroll
      for (int ni = 0; ni < 4; ni++)
        acc[mi][ni] = __builtin_amdgcn_mfma_f32_16x16x32_bf16(af[mi], bf[ni], acc[mi][ni], 0, 0, 0);
    __syncthreads();
  }

  // epilogue: bias, store f16 H, fused si/sj
  const int head0 = (n0 + wn) >> 5;
  const int head1 = head0 + 1;
  float c1a0 = A[head0 * 64 + l15],      c1a1 = A[head0 * 64 + 16 + l15];
  float c2a0 = A[head0 * 64 + 32 + l15], c2a1 = A[head0 * 64 + 48 + l15];
  float c1b0 = A[head1 * 64 + l15],      c1b1 = A[head1 * 64 + 16 + l15];
  float c2b0 = A[head1 * 64 + 32 + l15], c2b1 = A[head1 * 64 + 48 + l15];

#pragma unroll
  for (int mi = 0; mi < 4; mi++) {
    // bias (per-col)
#pragma unroll
    for (int ni = 0; ni < 4; ni++) {
      float b = bw[n0 + wn + ni * 16 + l15];
#pragma unroll
      for (int r = 0; r < 4; r++) acc[mi][ni][r] += b;
    }
    // store H (f16, 1-op cvt)
    const int rbase = m0 + wm + mi * 16 + quad * 4;
#pragma unroll
    for (int r = 0; r < 4; r++) {
      int node = rbase + r;
      if (node < N_NODES) {
#pragma unroll
        for (int ni = 0; ni < 4; ni++) {
          int col = n0 + wn + ni * 16 + l15;
          Hb[node * HID + col] = __float2half_rn(acc[mi][ni][r]);
        }
      }
    }
    // si/sj: dot over head dims via intra-quad shuffle reduce
    float s1a[4], s2a[4], s1b[4], s2b[4];
#pragma unroll
    for (int r = 0; r < 4; r++) {
      s1a[r] = acc[mi][0][r] * c1a0 + acc[mi][1][r] * c1a1;
      s2a[r] = acc[mi][0][r] * c2a0 + acc[mi][1][r] * c2a1;
      s1b[r] = acc[mi][2][r] * c1b0 + acc[mi][3][r] * c1b1;
      s2b[r] = acc[mi][2][r] * c2b0 + acc[mi][3][r] * c2b1;
    }
#pragma unroll
    for (int off = 1; off <= 8; off <<= 1) {
#pragma unroll
      for (int r = 0; r < 4; r++) {
        s1a[r] += __shfl_xor(s1a[r], off);
        s2a[r] += __shfl_xor(s2a[r], off);
        s1b[r] += __shfl_xor(s1b[r], off);
        s2b[r] += __shfl_xor(s2b[r], off);
      }
    }
    if (l15 == 0) {
#pragma unroll
      for (int r = 0; r < 4; r++) {
        int node = rbase + r;
        if (node < N_NODES) {
          si[node * HEADS + head0] = s1a[r];
          sj[node * HEADS + head0] = s2a[r];
          si[node * HEADS + head1] = s1b[r];
          sj[node * HEADS + head1] = s2b[r];
        }
      }
    }
  }
}

// ---------------- counting sort of edges by target ----------------
__global__ void k_hist(const int* __restrict__ tgt, int* __restrict__ cnt) {
  int e = blockIdx.x * 256 + threadIdx.x;
  if (e < N_EDGES) atomicAdd(&cnt[tgt[e]], 1);
}

__global__ __launch_bounds__(256) void k_scan1(const int* __restrict__ cnt,
    int* __restrict__ excl, int* __restrict__ bsum) {
  __shared__ int s[256];
  const int t = threadIdx.x;
  const int i = blockIdx.x * 256 + t;
  int v = (i < N_NODES) ? cnt[i] : 0;
  s[t] = v;
  __syncthreads();
  int x = v;
  for (int off = 1; off < 256; off <<= 1) {
    int y = (t >= off) ? s[t - off] : 0;
    __syncthreads();
    x += y;
    s[t] = x;
    __syncthreads();
  }
  if (i < N_NODES) excl[i] = x - v;
  if (t == 255) bsum[blockIdx.x] = x;
}

__global__ __launch_bounds__(256) void k_scan2(const int* __restrict__ bsum,
                                               int* __restrict__ boff) {
  __shared__ int s[256];
  const int t = threadIdx.x;
  int v = (t < 196) ? bsum[t] : 0;
  s[t] = v;
  __syncthreads();
  int x = v;
  for (int off = 1; off < 256; off <<= 1) {
    int y = (t >= off) ? s[t - off] : 0;
    __syncthreads();
    x += y;
    s[t] = x;
    __syncthreads();
  }
  if (t < 196) boff[t] = x - v;
}

__global__ void k_scan3(const int* __restrict__ excl, const int* __restrict__ boff,
                        int* __restrict__ rowptr, int* __restrict__ cursor) {
  int i = blockIdx.x * 256 + threadIdx.x;
  if (i < N_NODES) {
    int v = excl[i] + boff[blockIdx.x];
    rowptr[i] = v;
    cursor[i] = v;
  }
}

__global__ void k_scatter(const int* __restrict__ tgt, const int* __restrict__ src,
                          int* __restrict__ cursor, int* __restrict__ sortedSrc) {
  int e = blockIdx.x * 256 + threadIdx.x;
  if (e < N_EDGES) {
    int tg = tgt[e];
    int pos = atomicAdd(&cursor[tg], 1);
    sortedSrc[pos] = src[e];
  }
}

// ---------------- fused: softmax-agg + skip + ELU + LN + head-mean + Wout + ELU
// Round-3 structure: barrier-free direct gather loop. Each thread owns edge
// slots {es, es+8, ...} and cols cg*8..cg*8+7; recomputes (s, exv) per-lane
// (duplicate lanes share the wave instruction -- no extra wave-level cost),
// so the LDS stage + 2 barriers per tile and the 1.47x tail waste are gone.
__global__ __launch_bounds__(256) void k_fused(
    const __half* __restrict__ Hb, const float* __restrict__ si,
    const float* __restrict__ sj, const float* __restrict__ ba,
    const float* __restrict__ gamma, const float* __restrict__ beta,
    const float* __restrict__ Wout, const float* __restrict__ bout,
    const int* __restrict__ rowptr, const int* __restrict__ cnt,
    const int* __restrict__ sortedSrc, float* __restrict__ out) {
  __shared__ float accsT[8][8][33];  // [j][es][cg]: writes+reads <=2-way (free)
  __shared__ float dens[8][32];      // [es][cg]
  __shared__ float lnorm[256];
  __shared__ __align__(16) float meanv[32];

  const int n = blockIdx.x;
  const int t = threadIdx.x;
  const int cg = t & 31;           // col group: cols cg*8 .. cg*8+7
  const int es = t >> 5;           // edge-slot stride lane 0..7
  const int hh = cg >> 2;          // head of this col group
  const int start = rowptr[n];
  const int deg = cnt[n];

  const float sb = si[n * HEADS + hh] + ba[hh];   // broadcast line, no LDS
  const char* hbBase = (const char*)Hb + 16 * cg; // loop-invariant gather base
  const int* ss = sortedSrc + start;

  float acc[8] = {0.f, 0.f, 0.f, 0.f, 0.f, 0.f, 0.f, 0.f};
  float den = 0.f;
#pragma unroll 4
  for (int slot = es; slot < deg; slot += 8) {
    int s = ss[slot];                              // 2 addrs/wave, L1 broadcast
    float e = sb + sj[s * HEADS + hh];             // 1 line per edge
    e = (e >= 0.f) ? e : 0.2f * e;
    float exv = __expf(e);
    float4 hb4 = *(const float4*)(hbBase + (size_t)s * (HID * 2));
    const __half2* hp = (const __half2*)&hb4;
#pragma unroll
    for (int d = 0; d < 4; d++) {
      // fma(fpext(f16), f32, f32) -> v_fma_mix_f32 (no unpack ops)
      acc[2 * d]     += exv * __low2float(hp[d]);
      acc[2 * d + 1] += exv * __high2float(hp[d]);
    }
    den += exv;
  }

  // cross-es reduction (transposed layout: conflict-free)
#pragma unroll
  for (int j = 0; j < 8; j++) accsT[j][es][cg] = acc[j];
  dens[es][cg] = den;
  __syncthreads();

  float accT = 0.f, denT = 0.f;
#pragma unroll
  for (int e2 = 0; e2 < 8; e2++) {
    accT += accsT[t & 7][e2][t >> 3];
    denT += dens[e2][t >> 3];
  }
  float hs = __half2float(Hb[n * HID + t]);
  float v = ((deg > 0) ? __fdividef(accT, denT) : 0.f) + hs;
  v = (v > 0.f) ? v : (__expf(v) - 1.f);        // fast ELU
  float sum = v, sq = v * v;
#pragma unroll
  for (int off = 16; off >= 1; off >>= 1) {
    sum += __shfl_xor(sum, off);
    sq  += __shfl_xor(sq, off);
  }
  float mu = sum * (1.f / 32.f);
  float var = sq * (1.f / 32.f) - mu * mu;
  float nv = (v - mu) * rsqrtf(var + 1e-5f) * gamma[t] + beta[t];
  lnorm[t] = nv;
  __syncthreads();
  if (t < 32) {
    float m2 = 0.f;
#pragma unroll
    for (int h2 = 0; h2 < HEADS; h2++) m2 += lnorm[h2 * 32 + t];
    meanv[t] = m2 * 0.125f;
  }
  __syncthreads();
  // Output projection: coalesced dword loads (lane-consecutive addresses).
  // NOTE: do NOT transpose Wout for per-thread-contiguous float4 loads — that
  // puts lanes 128 B apart (64 L1 lines per wave instr) and cost +125 us in R1.
  float y = bout[t];
#pragma unroll
  for (int k = 0; k < 32; k++) y += meanv[k] * Wout[k * HID + t];
  y = (y > 0.f) ? y : (__expf(y) - 1.f);        // fast ELU
  out[n * HID + t] = y;
}

extern "C" void kernel_launch(void* const* d_in, const int* in_sizes, int n_in,
                              void* d_out, int out_size, void* d_ws, size_t ws_size,
                              hipStream_t stream) {
  const float* X     = (const float*)d_in[0];
  const int*   EI    = (const int*)d_in[1];
  const float* W     = (const float*)d_in[2];
  const float* bw    = (const float*)d_in[3];
  const float* A     = (const float*)d_in[4];
  const float* ba    = (const float*)d_in[5];
  const float* gamma = (const float*)d_in[6];
  const float* beta  = (const float*)d_in[7];
  const float* Wout  = (const float*)d_in[8];
  const float* bout  = (const float*)d_in[9];
  float* out = (float*)d_out;
  const int* tgt = EI;
  const int* src = EI + N_EDGES;

  char* ws = (char*)d_ws;
  size_t off = 0;
  auto alloc = [&](size_t bytes) -> void* {
    void* p = ws + off;
    off += bytes;
    off = (off + 255) & ~(size_t)255;
    return p;
  };
  __half* Hb       = (__half*)alloc((size_t)N_NODES * HID * 2);
  float* si        = (float*)alloc((size_t)N_NODES * HEADS * 4);
  float* sj        = (float*)alloc((size_t)N_NODES * HEADS * 4);
  int*   cnt       = (int*)  alloc((size_t)N_NODES * 4);
  int*   excl      = (int*)  alloc((size_t)N_NODES * 4);
  int*   bsum      = (int*)  alloc(256 * 4);
  int*   boff      = (int*)  alloc(256 * 4);
  int*   rowptr    = (int*)  alloc((size_t)N_NODES * 4);
  int*   cursor    = (int*)  alloc((size_t)N_NODES * 4);
  int*   sortedSrc = (int*)  alloc((size_t)N_EDGES * 4);

  hipMemsetAsync(cnt, 0, (size_t)N_NODES * 4, stream);
  k_hist<<<(N_EDGES + 255) / 256, 256, 0, stream>>>(tgt, cnt);
  k_scan1<<<196, 256, 0, stream>>>(cnt, excl, bsum);
  k_scan2<<<1, 256, 0, stream>>>(bsum, boff);
  k_scan3<<<196, 256, 0, stream>>>(excl, boff, rowptr, cursor);
  k_scatter<<<(N_EDGES + 255) / 256, 256, 0, stream>>>(tgt, src, cursor, sortedSrc);
  k_gemm<<<((N_NODES + 127) / 128) * 2, 256, 0, stream>>>(X, W, bw, A, Hb, si, sj);
  k_fused<<<N_NODES, 256, 0, stream>>>(Hb, si, sj, ba, gamma, beta, Wout, bout,
                                       rowptr, cnt, sortedSrc, out);
}

// Round 4
// 495.888 us; speedup vs baseline: 1.0550x; 1.0550x over previous
//
#include <hip/hip_runtime.h>
#include <hip/hip_bf16.h>
#include <hip/hip_fp16.h>

#define N_NODES 50000
#define N_EDGES 1600000
#define HEADS 8
#define HD 32
#define FIN 256
#define HID 256

typedef unsigned short u16;
typedef unsigned int u32;

typedef short s8v __attribute__((ext_vector_type(8)));   // 8 bf16 (4 VGPRs)
typedef float f4v __attribute__((ext_vector_type(4)));   // 4 fp32 acc
typedef float fx4 __attribute__((ext_vector_type(4)));   // clang vec (NT-able)

// pack 2 fp32 -> 2 bf16 (RNE) in one u32; lowers to v_cvt_pk_bf16_f32 on gfx950
__device__ __forceinline__ u32 pk2(float lo, float hi) {
  __hip_bfloat162 b = __float22bfloat162_rn(make_float2(lo, hi));
  union { __hip_bfloat162 b2; u32 u; } c;
  c.b2 = b;
  return c.u;
}

// ---------------- MFMA GEMM + fused attn projections ------------------------
// H[n][h*32+d] = X[n,:] @ W[h,:,d] + bw[h,d], stored f16.
// Round 4: 128x256 tile (all heads per block) -> X fetched ONCE (was twice).
// Block: 512 thr = 8 waves (2 row-groups x 4 col-groups of 64x64).
__global__ __launch_bounds__(512) void k_gemm(
    const float* __restrict__ X, const float* __restrict__ W,
    const float* __restrict__ bw, const float* __restrict__ A,
    __half* __restrict__ Hb, float* __restrict__ si, float* __restrict__ sj) {
  __shared__ __align__(16) u16 Xs[128 * 40];  // [row][k] stride 40 (2-way max)
  __shared__ __align__(16) u16 Wt[256 * 40];  // [col][k] stride 40

  const int t = threadIdx.x;
  const int m0 = blockIdx.x * 128;
  const int w = t >> 6;
  const int lane = t & 63;
  const int l15 = lane & 15;
  const int quad = lane >> 4;
  const int wm = (w >> 2) * 64;   // wave row offset in block tile
  const int wn = (w & 3) * 64;    // wave col offset in block tile

  f4v acc[4][4];
#pragma unroll
  for (int i = 0; i < 4; i++)
#pragma unroll
    for (int j = 0; j < 4; j++) acc[i][j] = (f4v){0.f, 0.f, 0.f, 0.f};

  // W staging assignment (constant over k-loop)
  const int nl = t & 255;          // local col (= global col: single col-tile)
  const int half = t >> 8;         // k half (0/1): kk = half*16 + i
  const int gh = nl >> 5, gd = nl & 31;

  for (int k0 = 0; k0 < FIN; k0 += 32) {
    // stage X tile: 128 rows x 32 k (fp32 -> bf16), read ONCE globally -> NT
#pragma unroll
    for (int p = 0; p < 2; p++) {
      int row = p * 64 + (t >> 3);
      int f4 = t & 7;
      int node = m0 + row;
      fx4 xv = (fx4){0.f, 0.f, 0.f, 0.f};
      if (node < N_NODES)
        xv = __builtin_nontemporal_load((const fx4*)&X[node * FIN + k0 + f4 * 4]);
      u32* dst = (u32*)&Xs[row * 40 + f4 * 4];
      dst[0] = pk2(xv[0], xv[1]);
      dst[1] = pk2(xv[2], xv[3]);
    }
    // stage W tile transposed: Wt[col][kk] = W[h][k0+kk][d] (small, keep cached)
    {
      const float* wp = W + gh * (FIN * HD) + (k0 + half * 16) * HD + gd;
#pragma unroll
      for (int j = 0; j < 8; j++) {
        float lo = wp[(2 * j) * HD];
        float hi = wp[(2 * j + 1) * HD];
        *(u32*)&Wt[nl * 40 + half * 16 + 2 * j] = pk2(lo, hi);
      }
    }
    __syncthreads();
    s8v af[4], bf[4];
#pragma unroll
    for (int mi = 0; mi < 4; mi++)
      af[mi] = *(const s8v*)&Xs[(wm + mi * 16 + l15) * 40 + quad * 8];
#pragma unroll
    for (int ni = 0; ni < 4; ni++)
      bf[ni] = *(const s8v*)&Wt[(wn + ni * 16 + l15) * 40 + quad * 8];
#pragma unroll
    for (int mi = 0; mi < 4; mi++)
#pragma unroll
      for (int ni = 0; ni < 4; ni++)
        acc[mi][ni] = __builtin_amdgcn_mfma_f32_16x16x32_bf16(af[mi], bf[ni], acc[mi][ni], 0, 0, 0);
    __syncthreads();
  }

  // epilogue: bias, store f16 H, fused si/sj
  const int head0 = wn >> 5;
  const int head1 = head0 + 1;
  float c1a0 = A[head0 * 64 + l15],      c1a1 = A[head0 * 64 + 16 + l15];
  float c2a0 = A[head0 * 64 + 32 + l15], c2a1 = A[head0 * 64 + 48 + l15];
  float c1b0 = A[head1 * 64 + l15],      c1b1 = A[head1 * 64 + 16 + l15];
  float c2b0 = A[head1 * 64 + 32 + l15], c2b1 = A[head1 * 64 + 48 + l15];

#pragma unroll
  for (int mi = 0; mi < 4; mi++) {
    // bias (per-col)
#pragma unroll
    for (int ni = 0; ni < 4; ni++) {
      float b = bw[wn + ni * 16 + l15];
#pragma unroll
      for (int r = 0; r < 4; r++) acc[mi][ni][r] += b;
    }
    // store H (f16, 1-op cvt)
    const int rbase = m0 + wm + mi * 16 + quad * 4;
#pragma unroll
    for (int r = 0; r < 4; r++) {
      int node = rbase + r;
      if (node < N_NODES) {
#pragma unroll
        for (int ni = 0; ni < 4; ni++) {
          int col = wn + ni * 16 + l15;
          Hb[node * HID + col] = __float2half_rn(acc[mi][ni][r]);
        }
      }
    }
    // si/sj: dot over head dims via intra-quad shuffle reduce
    float s1a[4], s2a[4], s1b[4], s2b[4];
#pragma unroll
    for (int r = 0; r < 4; r++) {
      s1a[r] = acc[mi][0][r] * c1a0 + acc[mi][1][r] * c1a1;
      s2a[r] = acc[mi][0][r] * c2a0 + acc[mi][1][r] * c2a1;
      s1b[r] = acc[mi][2][r] * c1b0 + acc[mi][3][r] * c1b1;
      s2b[r] = acc[mi][2][r] * c2b0 + acc[mi][3][r] * c2b1;
    }
#pragma unroll
    for (int off = 1; off <= 8; off <<= 1) {
#pragma unroll
      for (int r = 0; r < 4; r++) {
        s1a[r] += __shfl_xor(s1a[r], off);
        s2a[r] += __shfl_xor(s2a[r], off);
        s1b[r] += __shfl_xor(s1b[r], off);
        s2b[r] += __shfl_xor(s2b[r], off);
      }
    }
    if (l15 == 0) {
#pragma unroll
      for (int r = 0; r < 4; r++) {
        int node = rbase + r;
        if (node < N_NODES) {
          si[node * HEADS + head0] = s1a[r];
          sj[node * HEADS + head0] = s2a[r];
          si[node * HEADS + head1] = s1b[r];
          sj[node * HEADS + head1] = s2b[r];
        }
      }
    }
  }
}

// ---------------- counting sort of edges by target ----------------
__global__ void k_hist(const int* __restrict__ tgt, int* __restrict__ cnt) {
  int e = blockIdx.x * 256 + threadIdx.x;
  if (e < N_EDGES) atomicAdd(&cnt[tgt[e]], 1);
}

__global__ __launch_bounds__(256) void k_scan1(const int* __restrict__ cnt,
    int* __restrict__ excl, int* __restrict__ bsum) {
  __shared__ int s[256];
  const int t = threadIdx.x;
  const int i = blockIdx.x * 256 + t;
  int v = (i < N_NODES) ? cnt[i] : 0;
  s[t] = v;
  __syncthreads();
  int x = v;
  for (int off = 1; off < 256; off <<= 1) {
    int y = (t >= off) ? s[t - off] : 0;
    __syncthreads();
    x += y;
    s[t] = x;
    __syncthreads();
  }
  if (i < N_NODES) excl[i] = x - v;
  if (t == 255) bsum[blockIdx.x] = x;
}

__global__ __launch_bounds__(256) void k_scan2(const int* __restrict__ bsum,
                                               int* __restrict__ boff) {
  __shared__ int s[256];
  const int t = threadIdx.x;
  int v = (t < 196) ? bsum[t] : 0;
  s[t] = v;
  __syncthreads();
  int x = v;
  for (int off = 1; off < 256; off <<= 1) {
    int y = (t >= off) ? s[t - off] : 0;
    __syncthreads();
    x += y;
    s[t] = x;
    __syncthreads();
  }
  if (t < 196) boff[t] = x - v;
}

__global__ void k_scan3(const int* __restrict__ excl, const int* __restrict__ boff,
                        int* __restrict__ rowptr, int* __restrict__ cursor) {
  int i = blockIdx.x * 256 + threadIdx.x;
  if (i < N_NODES) {
    int v = excl[i] + boff[blockIdx.x];
    rowptr[i] = v;
    cursor[i] = v;
  }
}

__global__ void k_scatter(const int* __restrict__ tgt, const int* __restrict__ src,
                          int* __restrict__ cursor, int* __restrict__ sortedSrc) {
  int e = blockIdx.x * 256 + threadIdx.x;
  if (e < N_EDGES) {
    int tg = tgt[e];
    int pos = atomicAdd(&cursor[tg], 1);
    sortedSrc[pos] = src[e];
  }
}

// ---------------- fused: softmax-agg + skip + ELU + LN + head-mean + Wout + ELU
// Round-4 structure: WAVE-per-node. Block = 256 thr = 4 waves = 4 independent
// nodes. ZERO LDS, ZERO barriers. Per wave: lanes = es(2) x cg(32); cross-es
// reduce via shfl_xor(32); LN via 1/2-lane shuffles within 4-lane head groups;
// head-mean via 4/8/16 shuffles; Wout rows loaded as one coalesced dwordx4 per
// row (lane stride 16 B contiguous -- NOT the R1 128 B-stride trap).
__global__ __launch_bounds__(256) void k_fused(
    const __half* __restrict__ Hb, const float* __restrict__ si,
    const float* __restrict__ sj, const float* __restrict__ ba,
    const float* __restrict__ gamma, const float* __restrict__ beta,
    const float* __restrict__ Wout, const float* __restrict__ bout,
    const int* __restrict__ rowptr, const int* __restrict__ cnt,
    const int* __restrict__ sortedSrc, float* __restrict__ out) {
  const int t = threadIdx.x;
  const int lane = t & 63;
  const int n = blockIdx.x * 4 + (t >> 6);   // grid = 12500, 4 nodes/block exact
  const int cg = lane & 31;                  // col group: cols cg*8 .. cg*8+7
  const int es = lane >> 5;                  // edge-slot stride lane 0/1
  const int hh = cg >> 2;                    // head of this col group
  const int start = rowptr[n];
  const int deg = cnt[n];

  const float sb = si[n * HEADS + hh] + ba[hh];
  const char* hbBase = (const char*)Hb + 16 * cg;
  const int* ss = sortedSrc + start;

  float acc[8] = {0.f, 0.f, 0.f, 0.f, 0.f, 0.f, 0.f, 0.f};
  float den = 0.f;
#pragma unroll 4
  for (int slot = es; slot < deg; slot += 2) {
    int s = __builtin_nontemporal_load(ss + slot);  // streamed, read-once
    float e = sb + sj[s * HEADS + hh];
    e = (e >= 0.f) ? e : 0.2f * e;
    float exv = __expf(e);
    float4 hb4 = *(const float4*)(hbBase + (size_t)s * (HID * 2));
    const __half2* hp = (const __half2*)&hb4;
#pragma unroll
    for (int d = 0; d < 4; d++) {
      // fma(fpext(f16), f32, f32) -> v_fma_mix_f32
      acc[2 * d]     += exv * __low2float(hp[d]);
      acc[2 * d + 1] += exv * __high2float(hp[d]);
    }
    den += exv;
  }
  // cross-es reduce: one shuffle (wave is 64-wide)
#pragma unroll
  for (int j = 0; j < 8; j++) acc[j] += __shfl_xor(acc[j], 32);
  den += __shfl_xor(den, 32);

  // skip connection + ELU for this lane's 8 cols
  float4 h4 = *(const float4*)((const char*)Hb + (size_t)n * (HID * 2) + 16 * cg);
  const __half2* hq = (const __half2*)&h4;
  float inv = (deg > 0) ? __fdividef(1.f, den) : 0.f;
  float v[8], sum = 0.f, sq = 0.f;
#pragma unroll
  for (int j = 0; j < 8; j++) {
    float hv = (j & 1) ? __high2float(hq[j >> 1]) : __low2float(hq[j >> 1]);
    float x = acc[j] * inv + hv;
    x = (x > 0.f) ? x : (__expf(x) - 1.f);
    v[j] = x;
    sum += x;
    sq += x * x;
  }
  // LayerNorm over the head's 32 cols: in-lane 8 + 4-lane group (xor 1,2)
  sum += __shfl_xor(sum, 1); sq += __shfl_xor(sq, 1);
  sum += __shfl_xor(sum, 2); sq += __shfl_xor(sq, 2);
  float mu = sum * (1.f / 32.f);
  float var = sq * (1.f / 32.f) - mu * mu;
  float rstd = rsqrtf(var + 1e-5f);
  fx4 g0 = *(const fx4*)&gamma[cg * 8];
  fx4 g1 = *(const fx4*)&gamma[cg * 8 + 4];
  fx4 b0 = *(const fx4*)&beta[cg * 8];
  fx4 b1 = *(const fx4*)&beta[cg * 8 + 4];
  float m2[8];
#pragma unroll
  for (int j = 0; j < 8; j++) {
    float g = (j < 4) ? g0[j] : g1[j - 4];
    float bb = (j < 4) ? b0[j] : b1[j - 4];
    m2[j] = (v[j] - mu) * rstd * g + bb;
  }
  // head-mean: sum over heads = lanes differing in cg bits 2..4
#pragma unroll
  for (int j = 0; j < 8; j++) {
    m2[j] += __shfl_xor(m2[j], 4);
    m2[j] += __shfl_xor(m2[j], 8);
    m2[j] += __shfl_xor(m2[j], 16);
  }
  // now lane with (cg&3)==q holds (8*meanv[q*8+j]) in m2[j]

  // Output projection: this lane owns cols 4*lane..4*lane+3.
  // Per d: ONE dwordx4 load covers the whole 1 KB Wout row (coalesced).
  fx4 y = *(const fx4*)&bout[4 * lane];
#pragma unroll
  for (int q = 0; q < 4; q++) {
    float mv[8];
#pragma unroll
    for (int j = 0; j < 8; j++) mv[j] = __shfl(m2[j], q) * 0.125f;
#pragma unroll
    for (int j = 0; j < 8; j++) {
      fx4 w4 = *(const fx4*)&Wout[(q * 8 + j) * HID + 4 * lane];
      y += mv[j] * w4;
    }
  }
#pragma unroll
  for (int c = 0; c < 4; c++) y[c] = (y[c] > 0.f) ? y[c] : (__expf(y[c]) - 1.f);
  // streamed output: NT store keeps Hb resident in L2
  __builtin_nontemporal_store(y, (fx4*)&out[(size_t)n * HID + 4 * lane]);
}

extern "C" void kernel_launch(void* const* d_in, const int* in_sizes, int n_in,
                              void* d_out, int out_size, void* d_ws, size_t ws_size,
                              hipStream_t stream) {
  const float* X     = (const float*)d_in[0];
  const int*   EI    = (const int*)d_in[1];
  const float* W     = (const float*)d_in[2];
  const float* bw    = (const float*)d_in[3];
  const float* A     = (const float*)d_in[4];
  const float* ba    = (const float*)d_in[5];
  const float* gamma = (const float*)d_in[6];
  const float* beta  = (const float*)d_in[7];
  const float* Wout  = (const float*)d_in[8];
  const float* bout  = (const float*)d_in[9];
  float* out = (float*)d_out;
  const int* tgt = EI;
  const int* src = EI + N_EDGES;

  char* ws = (char*)d_ws;
  size_t off = 0;
  auto alloc = [&](size_t bytes) -> void* {
    void* p = ws + off;
    off += bytes;
    off = (off + 255) & ~(size_t)255;
    return p;
  };
  __half* Hb       = (__half*)alloc((size_t)N_NODES * HID * 2);
  float* si        = (float*)alloc((size_t)N_NODES * HEADS * 4);
  float* sj        = (float*)alloc((size_t)N_NODES * HEADS * 4);
  int*   cnt       = (int*)  alloc((size_t)N_NODES * 4);
  int*   excl      = (int*)  alloc((size_t)N_NODES * 4);
  int*   bsum      = (int*)  alloc(256 * 4);
  int*   boff      = (int*)  alloc(256 * 4);
  int*   rowptr    = (int*)  alloc((size_t)N_NODES * 4);
  int*   cursor    = (int*)  alloc((size_t)N_NODES * 4);
  int*   sortedSrc = (int*)  alloc((size_t)N_EDGES * 4);

  hipMemsetAsync(cnt, 0, (size_t)N_NODES * 4, stream);
  k_hist<<<(N_EDGES + 255) / 256, 256, 0, stream>>>(tgt, cnt);
  k_scan1<<<196, 256, 0, stream>>>(cnt, excl, bsum);
  k_scan2<<<1, 256, 0, stream>>>(bsum, boff);
  k_scan3<<<196, 256, 0, stream>>>(excl, boff, rowptr, cursor);
  k_scatter<<<(N_EDGES + 255) / 256, 256, 0, stream>>>(tgt, src, cursor, sortedSrc);
  k_gemm<<<(N_NODES + 127) / 128, 512, 0, stream>>>(X, W, bw, A, Hb, si, sj);
  k_fused<<<(N_NODES + 3) / 4, 256, 0, stream>>>(Hb, si, sj, ba, gamma, beta,
                                                 Wout, bout, rowptr, cnt,
                                                 sortedSrc, out);
}